// Round 8
// baseline (1444.630 us; speedup 1.0000x reference)
//
#include <hip/hip_runtime.h>
#include <math.h>

#define NR 131072
#define KC 1024
#define DD 256

// d_out element offsets (float32 elements)
#define ZQ_OFF  0
#define RES_OFF 33554432
#define IDX_OFF 67108864
#define LOSS_OFF 67239936
#define PERP_OFF 67239937

// ws byte offsets (total 40 KB)
#define WS_CNT 0        // int[1024]
#define WS_C2N 4096     // float[1024]
#define WS_BSS 8192     // double[4096]

#define FM(x,y) __fmul_rn((x),(y))
#define FA(x,y) __fadd_rn((x),(y))

// async global->LDS, 16B per lane; LDS dest = wave-uniform base + lane*16
static __device__ __forceinline__ void glds16(const float* g, float* l) {
  __builtin_amdgcn_global_load_lds(
      (const __attribute__((address_space(1))) void*)g,
      (__attribute__((address_space(3))) void*)l, 16, 0, 0);
}

// ---- numpy f32 pairwise sum-of-squares, one 128-block (AVX512 tree) --------
static __device__ __forceinline__ float np_sumsq128(const float* __restrict__ q) {
  float lane[16];
#pragma unroll
  for (int l = 0; l < 16; l++) {
    float s0 = FM(q[l +   0], q[l +   0]);
    float s1 = FM(q[l +  16], q[l +  16]);
    float s2 = FM(q[l +  32], q[l +  32]);
    float s3 = FM(q[l +  48], q[l +  48]);
    float s4 = FM(q[l +  64], q[l +  64]);
    float s5 = FM(q[l +  80], q[l +  80]);
    float s6 = FM(q[l +  96], q[l +  96]);
    float s7 = FM(q[l + 112], q[l + 112]);
    lane[l] = FA(FA(FA(s0, s1), FA(s2, s3)), FA(FA(s4, s5), FA(s6, s7)));
  }
#pragma unroll
  for (int h = 8; h >= 1; h >>= 1)
#pragma unroll
    for (int l = 0; l < 8; l++)
      if (l < h) lane[l] = FA(lane[l], lane[l + h]);
  return lane[0];
}

static __device__ __forceinline__ float np_sumsq256(const float* __restrict__ p) {
  return FA(np_sumsq128(p), np_sumsq128(p + 128));
}

// same tree, reading the XOR-swizzled zt half-tile (row r, logical k 0..127)
static __device__ __forceinline__ float np_sumsq128_swz(const float* __restrict__ zt,
                                                        int r) {
  const int xr = r & 3;
  const float* base = zt + r * 128;
  float lane[16];
#pragma unroll
  for (int l = 0; l < 16; l++) {
    float s[8];
#pragma unroll
    for (int m = 0; m < 8; m++) {
      const int k = l + 16 * m;
      const float v = base[((((k >> 2) ^ xr) << 2) | (k & 3))];
      s[m] = FM(v, v);
    }
    lane[l] = FA(FA(FA(s[0], s[1]), FA(s[2], s[3])), FA(FA(s[4], s[5]), FA(s[6], s[7])));
  }
#pragma unroll
  for (int h = 8; h >= 1; h >>= 1)
#pragma unroll
    for (int l = 0; l < 8; l++)
      if (l < h) lane[l] = FA(lane[l], lane[l + h]);
  return lane[0];
}

// ---------------- K1: codebook c2 (numpy-replica f32) -----------------------
__global__ void vq8_c2(const float* __restrict__ cb, float* __restrict__ c2n) {
  const int code = blockIdx.x * 256 + threadIdx.x;
  if (code < KC) c2n[code] = np_sumsq256(cb + (size_t)code * DD);
}

// ---------------- K2: fused np-f32 argmin + gather + outputs ----------------
// 32 rows/WG (4096 WGs), 16 chunks of 64 codes, per-thread 2 rows x 4 codes.
// zt [32][128] (half-K, slot^(row&3) swizzle), sc [64][32] (slot^(code&7)),
// both staged with global_load_lds (linear LDS dest, swizzled GLOBAL src).
// Bit-exact: each acc gets its 256 FMAs in ascending k (kh,kc,k4,elem).
__global__ __launch_bounds__(256) void vq8_main(
    const float* __restrict__ z, const float* __restrict__ cb,
    const float* __restrict__ c2n,
    float* __restrict__ out, int* __restrict__ counts,
    double* __restrict__ bss) {
  __shared__ __align__(16) float zt[32 * 128];   // 16,384 B
  __shared__ __align__(16) float sc[64 * 32];    //  8,192 B (also merge area)
  __shared__ float z2b[32][2];
  __shared__ int rowidx[32];
  __shared__ double wred[4];

  const int tid = threadIdx.x;
  const int wg  = blockIdx.x;
  const int tr  = tid >> 4;            // 0..15 -> rows {tr, tr+16}
  const int tc  = tid & 15;            // 0..15 -> codes {tc+16j} per 64-chunk
  const int wv  = tid >> 6;            // wave 0..3
  const int ln  = tid & 63;            // lane
  const size_t zwg = (size_t)wg * 32 * DD;

  const int xrA = tr & 3;              // zt read swizzle (same for tr and tr+16)
  const int xcB = tc & 7;              // sc read swizzle (same for tc and tc+8j)

  float m1[2] = {INFINITY, INFINITY};
  int   i1[2] = {0, 0};

  for (int cbk = 0; cbk < 16; cbk++) {
    float acc[2][4];
#pragma unroll
    for (int i = 0; i < 2; i++)
#pragma unroll
      for (int j = 0; j < 4; j++) acc[i][j] = 0.f;

    for (int kh = 0; kh < 2; kh++) {
      // ---- stage zt(kh) : 4 glds calls/wave, 2 rows each ----
#pragma unroll
      for (int j = 0; j < 4; j++) {
        const int r0  = wv * 8 + j * 2;
        const int row = r0 + (ln >> 5);
        const int p   = ln & 31;
        glds16(z + zwg + (size_t)row * DD + kh * 128 + ((p ^ (row & 3)) << 2),
               &zt[r0 * 128]);
      }
      // ---- stage sc(kc=0) : 2 glds calls/wave, 8 codes each ----
#pragma unroll
      for (int j = 0; j < 2; j++) {
        const int c0   = wv * 16 + j * 8;
        const int code = c0 + (ln >> 3);
        const int s    = ln & 7;
        glds16(cb + (size_t)(cbk * 64 + code) * DD + kh * 128 +
                   ((s ^ (code & 7)) << 2),
               &sc[c0 * 32]);
      }
      __syncthreads();                 // drains vmcnt -> tiles visible

      if (cbk == 0 && tid < 32) z2b[tid][kh] = np_sumsq128_swz(zt, tid);

      for (int kc = 0; kc < 4; kc++) {
#pragma unroll
        for (int k4 = 0; k4 < 8; k4++) {
          const int b = kc * 8 + k4;
          const float4 A0 = *(const float4*)&zt[(tr     ) * 128 + ((b ^ xrA) << 2)];
          const float4 A1 = *(const float4*)&zt[(tr + 16) * 128 + ((b ^ xrA) << 2)];
          float4 B[4];
#pragma unroll
          for (int j = 0; j < 4; j++)
            B[j] = *(const float4*)&sc[(tc + 16 * j) * 32 + ((k4 ^ xcB) << 2)];
          // strict ascending-k f32 FMA chain per (row, code)
#pragma unroll
          for (int j = 0; j < 4; j++) {
            acc[0][j] = __fmaf_rn(A0.x, B[j].x, acc[0][j]);
            acc[0][j] = __fmaf_rn(A0.y, B[j].y, acc[0][j]);
            acc[0][j] = __fmaf_rn(A0.z, B[j].z, acc[0][j]);
            acc[0][j] = __fmaf_rn(A0.w, B[j].w, acc[0][j]);
            acc[1][j] = __fmaf_rn(A1.x, B[j].x, acc[1][j]);
            acc[1][j] = __fmaf_rn(A1.y, B[j].y, acc[1][j]);
            acc[1][j] = __fmaf_rn(A1.z, B[j].z, acc[1][j]);
            acc[1][j] = __fmaf_rn(A1.w, B[j].w, acc[1][j]);
          }
        }
        __syncthreads();               // readers done before restage
        if (kc < 3) {
#pragma unroll
          for (int j = 0; j < 2; j++) {
            const int c0   = wv * 16 + j * 8;
            const int code = c0 + (ln >> 3);
            const int s    = ln & 7;
            glds16(cb + (size_t)(cbk * 64 + code) * DD + kh * 128 +
                       (kc + 1) * 32 + ((s ^ (code & 7)) << 2),
                   &sc[c0 * 32]);
          }
          __syncthreads();
        }
      }
    }

    // fold: d = fl( fl(z2 - 2*dot) + c2 ), first-min by ascending code
    float z2v[2];
    z2v[0] = FA(z2b[tr][0],      z2b[tr][1]);
    z2v[1] = FA(z2b[tr + 16][0], z2b[tr + 16][1]);
#pragma unroll
    for (int j = 0; j < 4; j++) {
      const int code = cbk * 64 + j * 16 + tc;
      const float c2v = c2n[code];
#pragma unroll
      for (int i = 0; i < 2; i++) {
        const float t1 = 2.0f * acc[i][j];           // exact (x2)
        const float d  = FA(FA(z2v[i], -t1), c2v);
        if (d < m1[i]) { m1[i] = d; i1[i] = code; }
      }
    }
  }

  // ---- cross-thread first-min merge (lexicographic on (d, code)) ----
  float* redm1 = sc;                   // [32][16] floats
  int*   redi1 = (int*)(sc + 512);     // [32][16] ints
  __syncthreads();                     // last compute readers done
#pragma unroll
  for (int i = 0; i < 2; i++) {
    const int r = tr + 16 * i;
    redm1[r * 16 + tc] = m1[i];
    redi1[r * 16 + tc] = i1[i];
  }
  __syncthreads();
  if (tid < 32) {
    float M1 = INFINITY; int I1 = 0x7FFFFFFF;
    for (int q = 0; q < 16; q++) {
      const float a = redm1[tid * 16 + q];
      const int  ia = redi1[tid * 16 + q];
      if (a < M1 || (a == M1 && ia < I1)) { M1 = a; I1 = ia; }
    }
    rowidx[tid] = I1;
    atomicAdd(&counts[I1], 1);
    out[IDX_OFF + wg * 32 + tid] = (float)I1;
  }
  __syncthreads();

  // ---- gather + zq_st / residual (float32) + loss partial ----
  const int rr  = tid >> 3;            // 0..31 row
  const int seg = tid & 7;             // 0..7, 32-float segment
  const int id  = rowidx[rr];
  const size_t zrow = zwg + (size_t)rr * DD + seg * 32;
  const float4* zp = (const float4*)(z + zrow);
  const float4* qp = (const float4*)(cb + (size_t)id * DD + seg * 32);
  float ss = 0.f;
#pragma unroll
  for (int u = 0; u < 8; u++) {
    const float4 r4 = zp[u];
    const float4 q4 = qp[u];
    float4 stv, rsv; float dq;
    stv.x = r4.x + (q4.x - r4.x); rsv.x = r4.x - q4.x; dq = q4.x - r4.x; ss = fmaf(dq, dq, ss);
    stv.y = r4.y + (q4.y - r4.y); rsv.y = r4.y - q4.y; dq = q4.y - r4.y; ss = fmaf(dq, dq, ss);
    stv.z = r4.z + (q4.z - r4.z); rsv.z = r4.z - q4.z; dq = q4.z - r4.z; ss = fmaf(dq, dq, ss);
    stv.w = r4.w + (q4.w - r4.w); rsv.w = r4.w - q4.w; dq = q4.w - r4.w; ss = fmaf(dq, dq, ss);
    *(float4*)(out + ZQ_OFF  + zrow + u * 4) = stv;
    *(float4*)(out + RES_OFF + zrow + u * 4) = rsv;
  }
  double dss = (double)ss;
  for (int o = 32; o; o >>= 1) dss += __shfl_down(dss, o, 64);
  if ((tid & 63) == 0) wred[tid >> 6] = dss;
  __syncthreads();
  if (tid == 0) bss[wg] = wred[0] + wred[1] + wred[2] + wred[3];
}

// ---------------- K3: scalars (loss, perplexity) ----------------------------
__global__ void vq8_final(const int* __restrict__ counts,
                          const double* __restrict__ bss,
                          float* __restrict__ out) {
  __shared__ double red[256];
  const int t = threadIdx.x;
  double s = 0.0;
  for (int i = t; i < 4096; i += 256) s += bss[i];
  red[t] = s; __syncthreads();
  for (int s2 = 128; s2 > 0; s2 >>= 1) { if (t < s2) red[t] += red[t + s2]; __syncthreads(); }
  const double ssq = red[0];
  __syncthreads();
  double h = 0.0;
  for (int c = t; c < 1024; c += 256) {
    double p = (double)counts[c] / 131072.0;
    h += p * log(p + 1e-10);
  }
  red[t] = h; __syncthreads();
  for (int s2 = 128; s2 > 0; s2 >>= 1) { if (t < s2) red[t] += red[t + s2]; __syncthreads(); }
  if (t == 0) {
    out[LOSS_OFF] = (float)(0.25 * ssq / 33554432.0);
    out[PERP_OFF] = (float)exp(-red[0]);
  }
}

extern "C" void kernel_launch(void* const* d_in, const int* in_sizes, int n_in,
                              void* d_out, int out_size, void* d_ws, size_t ws_size,
                              hipStream_t stream) {
  // Bind inputs by SIZE: z has 33,554,432 elems, codebook 262,144.
  const float* z;
  const float* cb;
  if (in_sizes[0] == NR * DD) { z = (const float*)d_in[0]; cb = (const float*)d_in[1]; }
  else                        { cb = (const float*)d_in[0]; z = (const float*)d_in[1]; }

  float* out = (float*)d_out;
  char* ws = (char*)d_ws;
  int*    counts = (int*)(ws + WS_CNT);
  float*  c2n    = (float*)(ws + WS_C2N);
  double* bss    = (double*)(ws + WS_BSS);

  hipMemsetAsync(counts, 0, 4096, stream);
  vq8_c2<<<4, 256, 0, stream>>>(cb, c2n);
  vq8_main<<<NR / 32, 256, 0, stream>>>(z, cb, c2n, out, counts, bss);
  vq8_final<<<1, 256, 0, stream>>>(counts, bss, out);
}

// Round 9
// 1404.469 us; speedup vs baseline: 1.0286x; 1.0286x over previous
//
#include <hip/hip_runtime.h>
#include <math.h>

#define NR 131072
#define KC 1024
#define DD 256

// d_out element offsets (float32 elements)
#define ZQ_OFF  0
#define RES_OFF 33554432
#define IDX_OFF 67108864
#define LOSS_OFF 67239936
#define PERP_OFF 67239937

// ws byte offsets (total ~549 KB)
#define WS_CNT 0         // int[1024]
#define WS_C2N 4096      // float[1024]
#define WS_Z2  8192      // float[131072]
#define WS_BSS 532480    // double[2048]

#define FM(x,y) __fmul_rn((x),(y))
#define FA(x,y) __fadd_rn((x),(y))

// async global->LDS, 16B/lane; LDS dest = wave-uniform base + lane*16
static __device__ __forceinline__ void glds16(const float* g, float* l) {
  __builtin_amdgcn_global_load_lds(
      (const __attribute__((address_space(1))) void*)g,
      (__attribute__((address_space(3))) void*)l, 16, 0, 0);
}

// ---- numpy f32 pairwise sum-of-squares, one 128-block (AVX512 tree) --------
static __device__ __forceinline__ float np_sumsq128(const float* __restrict__ q) {
  float lane[16];
#pragma unroll
  for (int l = 0; l < 16; l++) {
    float s0 = FM(q[l +   0], q[l +   0]);
    float s1 = FM(q[l +  16], q[l +  16]);
    float s2 = FM(q[l +  32], q[l +  32]);
    float s3 = FM(q[l +  48], q[l +  48]);
    float s4 = FM(q[l +  64], q[l +  64]);
    float s5 = FM(q[l +  80], q[l +  80]);
    float s6 = FM(q[l +  96], q[l +  96]);
    float s7 = FM(q[l + 112], q[l + 112]);
    lane[l] = FA(FA(FA(s0, s1), FA(s2, s3)), FA(FA(s4, s5), FA(s6, s7)));
  }
#pragma unroll
  for (int h = 8; h >= 1; h >>= 1)
#pragma unroll
    for (int l = 0; l < 8; l++)
      if (l < h) lane[l] = FA(lane[l], lane[l + h]);
  return lane[0];
}

static __device__ __forceinline__ float np_sumsq256(const float* __restrict__ p) {
  return FA(np_sumsq128(p), np_sumsq128(p + 128));
}

// ---------------- K1a: codebook c2 (numpy-replica f32) ----------------------
__global__ void vq9_c2(const float* __restrict__ cb, float* __restrict__ c2n) {
  const int code = blockIdx.x * 256 + threadIdx.x;
  if (code < KC) c2n[code] = np_sumsq256(cb + (size_t)code * DD);
}

// ---------------- K1b: per-row z2, 16 threads/row, exact AVX512 tree --------
// lane l computes lane[l] (8 squares, FA tree), then halving via shfl_down
// within the 16-lane group (h = 8,4,2,1) == _mm512_reduce_add_ps association.
__global__ void vq9_z2(const float* __restrict__ z, float* __restrict__ z2g) {
  const int row = blockIdx.x * 16 + (threadIdx.x >> 4);
  const int l   = threadIdx.x & 15;
  const float* q = z + (size_t)row * DD;
  float blk[2];
#pragma unroll
  for (int b = 0; b < 2; b++) {
    const float* qq = q + b * 128;
    const float s0 = FM(qq[l +   0], qq[l +   0]);
    const float s1 = FM(qq[l +  16], qq[l +  16]);
    const float s2 = FM(qq[l +  32], qq[l +  32]);
    const float s3 = FM(qq[l +  48], qq[l +  48]);
    const float s4 = FM(qq[l +  64], qq[l +  64]);
    const float s5 = FM(qq[l +  80], qq[l +  80]);
    const float s6 = FM(qq[l +  96], qq[l +  96]);
    const float s7 = FM(qq[l + 112], qq[l + 112]);
    float v = FA(FA(FA(s0, s1), FA(s2, s3)), FA(FA(s4, s5), FA(s6, s7)));
#pragma unroll
    for (int h = 8; h >= 1; h >>= 1) v = FA(v, __shfl_down(v, h, 16));
    blk[b] = v;
  }
  if (l == 0) z2g[row] = FA(blk[0], blk[1]);
}

// ---------------- K2: fused np-f32 argmin + gather + outputs ----------------
// 64 rows/WG (2048 WGs); 8 blocks of 128 codes; K-chunks of 32.
// Per-thread tile 4 rows x 8 codes. zt [64][32] slot^(row&3), sc [128][32]
// slot^(code&7); staged via global_load_lds (linear dest, swizzled global src).
// Bit-exact: each acc gets its 256 FMAs in ascending k (cbk,kq,k4,elem).
__global__ __launch_bounds__(256, 4) void vq9_main(
    const float* __restrict__ z, const float* __restrict__ cb,
    const float* __restrict__ c2n, const float* __restrict__ z2g,
    float* __restrict__ out, int* __restrict__ counts,
    double* __restrict__ bss) {
  __shared__ __align__(16) float zt[64 * 32];    //  8,192 B
  __shared__ __align__(16) float sc[128 * 32];   // 16,384 B (also merge area)
  __shared__ int rowidx[64];
  __shared__ double wred[4];

  const int tid = threadIdx.x;
  const int wg  = blockIdx.x;
  const int tr  = tid >> 4;            // 0..15 -> rows {tr+16i}
  const int tc  = tid & 15;            // 0..15 -> codes {tc+16j} per 128-chunk
  const int wv  = tid >> 6;            // wave 0..3
  const int ln  = tid & 63;
  const size_t zwg = (size_t)wg * 64 * DD;

  const int xA = tr & 3;               // zt read swizzle (const across i: 16i%4=0)
  const int xB = tc & 7;               // sc read swizzle (const across j: 16j%8=0)

  float z2v[4];
#pragma unroll
  for (int i = 0; i < 4; i++) z2v[i] = z2g[wg * 64 + tr + 16 * i];

  float m1[4]; int i1[4];
#pragma unroll
  for (int i = 0; i < 4; i++) { m1[i] = INFINITY; i1[i] = 0; }

  for (int cbk = 0; cbk < 8; cbk++) {
    float acc[4][8];
#pragma unroll
    for (int i = 0; i < 4; i++)
#pragma unroll
      for (int j = 0; j < 8; j++) acc[i][j] = 0.f;

    for (int kq = 0; kq < 8; kq++) {
      // ---- stage zt chunk: 2 glds/wave (8 rows each) ----
#pragma unroll
      for (int u = 0; u < 2; u++) {
        const int r0  = wv * 16 + u * 8;
        const int row = r0 + (ln >> 3);
        const int s   = ln & 7;
        glds16(z + zwg + (size_t)row * DD + kq * 32 + ((s ^ (row & 3)) << 2),
               &zt[r0 * 32]);
      }
      // ---- stage sc chunk: 4 glds/wave (8 codes each) ----
#pragma unroll
      for (int u = 0; u < 4; u++) {
        const int c0   = wv * 32 + u * 8;
        const int code = c0 + (ln >> 3);
        const int s    = ln & 7;
        glds16(cb + (size_t)(cbk * 128 + code) * DD + kq * 32 +
                   ((s ^ (code & 7)) << 2),
               &sc[c0 * 32]);
      }
      __syncthreads();                 // drain vmcnt -> tiles visible

#pragma unroll
      for (int k4 = 0; k4 < 8; k4++) {
        const int sA = (k4 ^ xA) << 2;
        const int sB = (k4 ^ xB) << 2;
        float4 A[4], B[8];
#pragma unroll
        for (int i = 0; i < 4; i++)
          A[i] = *(const float4*)&zt[(tr + 16 * i) * 32 + sA];
#pragma unroll
        for (int j = 0; j < 8; j++)
          B[j] = *(const float4*)&sc[(tc + 16 * j) * 32 + sB];
        // strict ascending-k f32 FMA chain per (row, code)
#pragma unroll
        for (int i = 0; i < 4; i++)
#pragma unroll
          for (int j = 0; j < 8; j++) {
            acc[i][j] = __fmaf_rn(A[i].x, B[j].x, acc[i][j]);
            acc[i][j] = __fmaf_rn(A[i].y, B[j].y, acc[i][j]);
            acc[i][j] = __fmaf_rn(A[i].z, B[j].z, acc[i][j]);
            acc[i][j] = __fmaf_rn(A[i].w, B[j].w, acc[i][j]);
          }
      }
      __syncthreads();                 // readers done before next restage
    }

    // fold 128 codes: d = fl( fl(z2 - 2*dot) + c2 ), first-min ascending code
#pragma unroll
    for (int j = 0; j < 8; j++) {
      const int code = cbk * 128 + j * 16 + tc;
      const float c2v = c2n[code];
#pragma unroll
      for (int i = 0; i < 4; i++) {
        const float t1 = 2.0f * acc[i][j];           // exact (x2)
        const float d  = FA(FA(z2v[i], -t1), c2v);
        if (d < m1[i]) { m1[i] = d; i1[i] = code; }
      }
    }
  }

  // ---- cross-thread first-min merge (lexicographic on (d, code)) ----
  float* redm1 = sc;                   // [64][16] floats
  int*   redi1 = (int*)(sc + 1024);    // [64][16] ints
#pragma unroll
  for (int i = 0; i < 4; i++) {
    const int r = tr + 16 * i;
    redm1[r * 16 + tc] = m1[i];
    redi1[r * 16 + tc] = i1[i];
  }
  __syncthreads();
  if (tid < 64) {
    float M1 = INFINITY; int I1 = 0x7FFFFFFF;
    for (int q = 0; q < 16; q++) {
      const float a = redm1[tid * 16 + q];
      const int  ia = redi1[tid * 16 + q];
      if (a < M1 || (a == M1 && ia < I1)) { M1 = a; I1 = ia; }
    }
    rowidx[tid] = I1;
    atomicAdd(&counts[I1], 1);
    out[IDX_OFF + wg * 64 + tid] = (float)I1;
  }
  __syncthreads();

  // ---- gather + zq_st / residual (float32) + loss partial ----
  const int rr  = tid >> 2;            // 0..63 row
  const int seg = tid & 3;             // 0..3, 64-float segment
  const int id  = rowidx[rr];
  const size_t zrow = zwg + (size_t)rr * DD + seg * 64;
  const float4* zp = (const float4*)(z + zrow);
  const float4* qp = (const float4*)(cb + (size_t)id * DD + seg * 64);
  float ss = 0.f;
#pragma unroll
  for (int u = 0; u < 16; u++) {
    const float4 r4 = zp[u];
    const float4 q4 = qp[u];
    float4 stv, rsv; float dq;
    stv.x = r4.x + (q4.x - r4.x); rsv.x = r4.x - q4.x; dq = q4.x - r4.x; ss = fmaf(dq, dq, ss);
    stv.y = r4.y + (q4.y - r4.y); rsv.y = r4.y - q4.y; dq = q4.y - r4.y; ss = fmaf(dq, dq, ss);
    stv.z = r4.z + (q4.z - r4.z); rsv.z = r4.z - q4.z; dq = q4.z - r4.z; ss = fmaf(dq, dq, ss);
    stv.w = r4.w + (q4.w - r4.w); rsv.w = r4.w - q4.w; dq = q4.w - r4.w; ss = fmaf(dq, dq, ss);
    *(float4*)(out + ZQ_OFF  + zrow + u * 4) = stv;
    *(float4*)(out + RES_OFF + zrow + u * 4) = rsv;
  }
  double dss = (double)ss;
  for (int o = 32; o; o >>= 1) dss += __shfl_down(dss, o, 64);
  if ((tid & 63) == 0) wred[tid >> 6] = dss;
  __syncthreads();
  if (tid == 0) bss[wg] = wred[0] + wred[1] + wred[2] + wred[3];
}

// ---------------- K3: scalars (loss, perplexity) ----------------------------
__global__ void vq9_final(const int* __restrict__ counts,
                          const double* __restrict__ bss,
                          float* __restrict__ out) {
  __shared__ double red[256];
  const int t = threadIdx.x;
  double s = 0.0;
  for (int i = t; i < 2048; i += 256) s += bss[i];
  red[t] = s; __syncthreads();
  for (int s2 = 128; s2 > 0; s2 >>= 1) { if (t < s2) red[t] += red[t + s2]; __syncthreads(); }
  const double ssq = red[0];
  __syncthreads();
  double h = 0.0;
  for (int c = t; c < 1024; c += 256) {
    double p = (double)counts[c] / 131072.0;
    h += p * log(p + 1e-10);
  }
  red[t] = h; __syncthreads();
  for (int s2 = 128; s2 > 0; s2 >>= 1) { if (t < s2) red[t] += red[t + s2]; __syncthreads(); }
  if (t == 0) {
    out[LOSS_OFF] = (float)(0.25 * ssq / 33554432.0);
    out[PERP_OFF] = (float)exp(-red[0]);
  }
}

extern "C" void kernel_launch(void* const* d_in, const int* in_sizes, int n_in,
                              void* d_out, int out_size, void* d_ws, size_t ws_size,
                              hipStream_t stream) {
  // Bind inputs by SIZE: z has 33,554,432 elems, codebook 262,144.
  const float* z;
  const float* cb;
  if (in_sizes[0] == NR * DD) { z = (const float*)d_in[0]; cb = (const float*)d_in[1]; }
  else                        { cb = (const float*)d_in[0]; z = (const float*)d_in[1]; }

  float* out = (float*)d_out;
  char* ws = (char*)d_ws;
  int*    counts = (int*)(ws + WS_CNT);
  float*  c2n    = (float*)(ws + WS_C2N);
  float*  z2g    = (float*)(ws + WS_Z2);
  double* bss    = (double*)(ws + WS_BSS);

  hipMemsetAsync(counts, 0, 4096, stream);
  vq9_c2<<<4, 256, 0, stream>>>(cb, c2n);
  vq9_z2<<<NR / 16, 256, 0, stream>>>(z, z2g);
  vq9_main<<<NR / 64, 256, 0, stream>>>(z, cb, c2n, z2g, out, counts, bss);
  vq9_final<<<1, 256, 0, stream>>>(counts, bss, out);
}

// Round 10
// 1001.665 us; speedup vs baseline: 1.4422x; 1.4021x over previous
//
#include <hip/hip_runtime.h>
#include <math.h>

#define NR 131072
#define KC 1024
#define DD 256

// d_out element offsets (float32 elements)
#define ZQ_OFF  0
#define RES_OFF 33554432
#define IDX_OFF 67108864
#define LOSS_OFF 67239936
#define PERP_OFF 67239937

// ws byte offsets
#define WS_CNT 0         // int[1024]
#define WS_C2N 4096      // float[1024]
#define WS_Z2  8192      // float[131072]
#define WS_BSS 532480    // double[512]

#define FM(x,y) __fmul_rn((x),(y))
#define FA(x,y) __fadd_rn((x),(y))

// async global->LDS, 16B/lane; LDS dest = wave-uniform base + lane*16
static __device__ __forceinline__ void glds16(const float* g, float* l) {
  __builtin_amdgcn_global_load_lds(
      (const __attribute__((address_space(1))) void*)g,
      (__attribute__((address_space(3))) void*)l, 16, 0, 0);
}

// ---- numpy f32 pairwise sum-of-squares, one 128-block (AVX512 tree) --------
static __device__ __forceinline__ float np_sumsq128(const float* __restrict__ q) {
  float lane[16];
#pragma unroll
  for (int l = 0; l < 16; l++) {
    float s0 = FM(q[l +   0], q[l +   0]);
    float s1 = FM(q[l +  16], q[l +  16]);
    float s2 = FM(q[l +  32], q[l +  32]);
    float s3 = FM(q[l +  48], q[l +  48]);
    float s4 = FM(q[l +  64], q[l +  64]);
    float s5 = FM(q[l +  80], q[l +  80]);
    float s6 = FM(q[l +  96], q[l +  96]);
    float s7 = FM(q[l + 112], q[l + 112]);
    lane[l] = FA(FA(FA(s0, s1), FA(s2, s3)), FA(FA(s4, s5), FA(s6, s7)));
  }
#pragma unroll
  for (int h = 8; h >= 1; h >>= 1)
#pragma unroll
    for (int l = 0; l < 8; l++)
      if (l < h) lane[l] = FA(lane[l], lane[l + h]);
  return lane[0];
}

static __device__ __forceinline__ float np_sumsq256(const float* __restrict__ p) {
  return FA(np_sumsq128(p), np_sumsq128(p + 128));
}

// ---------------- K1a: codebook c2 (numpy-replica f32) ----------------------
__global__ void vq10_c2(const float* __restrict__ cb, float* __restrict__ c2n) {
  const int code = blockIdx.x * 256 + threadIdx.x;
  if (code < KC) c2n[code] = np_sumsq256(cb + (size_t)code * DD);
}

// ---------------- K1b: per-row z2, 16 threads/row, exact AVX512 tree --------
__global__ void vq10_z2(const float* __restrict__ z, float* __restrict__ z2g) {
  const int row = blockIdx.x * 16 + (threadIdx.x >> 4);
  const int l   = threadIdx.x & 15;
  const float* q = z + (size_t)row * DD;
  float blk[2];
#pragma unroll
  for (int b = 0; b < 2; b++) {
    const float* qq = q + b * 128;
    const float s0 = FM(qq[l +   0], qq[l +   0]);
    const float s1 = FM(qq[l +  16], qq[l +  16]);
    const float s2 = FM(qq[l +  32], qq[l +  32]);
    const float s3 = FM(qq[l +  48], qq[l +  48]);
    const float s4 = FM(qq[l +  64], qq[l +  64]);
    const float s5 = FM(qq[l +  80], qq[l +  80]);
    const float s6 = FM(qq[l +  96], qq[l +  96]);
    const float s7 = FM(qq[l + 112], qq[l + 112]);
    float v = FA(FA(FA(s0, s1), FA(s2, s3)), FA(FA(s4, s5), FA(s6, s7)));
#pragma unroll
    for (int h = 8; h >= 1; h >>= 1) v = FA(v, __shfl_down(v, h, 16));
    blk[b] = v;
  }
  if (l == 0) z2g[row] = FA(blk[0], blk[1]);
}

// ---------------- K2: fused np-f32 argmin + gather + outputs ----------------
// 256 rows/WG (512 WGs); 8 blocks of 128 codes; K-chunks of 32.
// Per-thread tile 16 rows x 8 codes (i*j/(i+j)=5.33 -> LDS~FMA balanced).
// zt [256][32] slot^(row&3), sc [128][32] slot^(code&7), glds-staged
// (linear LDS dest, swizzled global src). Bit-exact: each acc gets its 256
// FMAs in ascending k (cbk,kq,k4,elem) == np/BLAS chain.
__global__ __launch_bounds__(256, 2) void vq10_main(
    const float* __restrict__ z, const float* __restrict__ cb,
    const float* __restrict__ c2n, const float* __restrict__ z2g,
    float* __restrict__ out, int* __restrict__ counts,
    double* __restrict__ bss) {
  __shared__ __align__(16) float zt[256 * 32];   // 32,768 B (also merge area)
  __shared__ __align__(16) float sc[128 * 32];   // 16,384 B
  __shared__ int rowidx[256];
  __shared__ double wred[4];

  const int tid = threadIdx.x;
  const int wg  = blockIdx.x;
  const int tr  = tid >> 4;            // 0..15 -> rows {tr+16i, i=0..15}
  const int tc  = tid & 15;            // 0..15 -> codes {tc+16j, j=0..7}
  const int wv  = tid >> 6;            // wave 0..3
  const int ln  = tid & 63;
  const size_t zwg = (size_t)wg * 256 * DD;

  const int xA = tr & 3;               // zt read swizzle ((tr+16i)&3 == tr&3)
  const int xB = tc & 7;               // sc read swizzle ((tc+16j)&7 == tc&7)

  float m1[16]; int i1[16];
#pragma unroll
  for (int i = 0; i < 16; i++) { m1[i] = INFINITY; i1[i] = 0; }

#pragma unroll 1
  for (int cbk = 0; cbk < 8; cbk++) {
    float acc[16][8];
#pragma unroll
    for (int i = 0; i < 16; i++)
#pragma unroll
      for (int j = 0; j < 8; j++) acc[i][j] = 0.f;

#pragma unroll 1
    for (int kq = 0; kq < 8; kq++) {
      // ---- stage zt chunk: 8 glds/wave (8 rows each) ----
#pragma unroll
      for (int u = 0; u < 8; u++) {
        const int r0  = wv * 64 + u * 8;
        const int row = r0 + (ln >> 3);
        const int s   = ln & 7;
        glds16(z + zwg + (size_t)row * DD + kq * 32 + ((s ^ (row & 3)) << 2),
               &zt[r0 * 32]);
      }
      // ---- stage sc chunk: 4 glds/wave (8 codes each) ----
#pragma unroll
      for (int u = 0; u < 4; u++) {
        const int c0   = wv * 32 + u * 8;
        const int code = c0 + (ln >> 3);
        const int s    = ln & 7;
        glds16(cb + (size_t)(cbk * 128 + code) * DD + kq * 32 +
                   ((s ^ (code & 7)) << 2),
               &sc[c0 * 32]);
      }
      __syncthreads();                 // drain -> tiles visible

#pragma unroll 2
      for (int k4 = 0; k4 < 8; k4++) {
        const int sA = (k4 ^ xA) << 2;
        const int sB = (k4 ^ xB) << 2;
        float4 B[8];
#pragma unroll
        for (int j = 0; j < 8; j++)
          B[j] = *(const float4*)&sc[(tc + 16 * j) * 32 + sB];
#pragma unroll
        for (int i = 0; i < 16; i++) {
          const float4 Av = *(const float4*)&zt[(tr + 16 * i) * 32 + sA];
          // strict ascending-k f32 FMA chain per (row, code)
#pragma unroll
          for (int j = 0; j < 8; j++) {
            acc[i][j] = __fmaf_rn(Av.x, B[j].x, acc[i][j]);
            acc[i][j] = __fmaf_rn(Av.y, B[j].y, acc[i][j]);
            acc[i][j] = __fmaf_rn(Av.z, B[j].z, acc[i][j]);
            acc[i][j] = __fmaf_rn(Av.w, B[j].w, acc[i][j]);
          }
        }
      }
      __syncthreads();                 // readers done before restage
    }

    // fold 128 codes: d = fl( fl(z2 - 2*dot) + c2 ), first-min ascending code
#pragma unroll
    for (int j = 0; j < 8; j++) {
      const int code = cbk * 128 + j * 16 + tc;
      const float c2v = c2n[code];
#pragma unroll
      for (int i = 0; i < 16; i++) {
        const float z2v = z2g[wg * 256 + tr + 16 * i];
        const float t1 = 2.0f * acc[i][j];           // exact (x2)
        const float d  = FA(FA(z2v, -t1), c2v);
        if (d < m1[i]) { m1[i] = d; i1[i] = code; }
      }
    }
  }

  // ---- cross-thread first-min merge (lexicographic on (d, code)) ----
  float* redm1 = zt;                   // [256][16] floats
  int*   redi1 = (int*)(zt + 4096);    // [256][16] ints
#pragma unroll
  for (int i = 0; i < 16; i++) {
    const int r = tr + 16 * i;
    redm1[r * 16 + tc] = m1[i];
    redi1[r * 16 + tc] = i1[i];
  }
  __syncthreads();
  {
    float M1 = INFINITY; int I1 = 0x7FFFFFFF;
    for (int q = 0; q < 16; q++) {
      const float a = redm1[tid * 16 + q];
      const int  ia = redi1[tid * 16 + q];
      if (a < M1 || (a == M1 && ia < I1)) { M1 = a; I1 = ia; }
    }
    rowidx[tid] = I1;
    atomicAdd(&counts[I1], 1);
    out[IDX_OFF + wg * 256 + tid] = (float)I1;
  }
  __syncthreads();

  // ---- gather + zq_st / residual (float32) + loss partial ----
  float ss = 0.f;
#pragma unroll 1
  for (int g = 0; g < 4; g++) {
    const int rr  = g * 64 + (tid >> 2);   // row
    const int seg = tid & 3;               // 64-float segment
    const int id  = rowidx[rr];
    const size_t zrow = zwg + (size_t)rr * DD + seg * 64;
    const float4* zp = (const float4*)(z + zrow);
    const float4* qp = (const float4*)(cb + (size_t)id * DD + seg * 64);
#pragma unroll
    for (int u = 0; u < 16; u++) {
      const float4 r4 = zp[u];
      const float4 q4 = qp[u];
      float4 stv, rsv; float dq;
      stv.x = r4.x + (q4.x - r4.x); rsv.x = r4.x - q4.x; dq = q4.x - r4.x; ss = fmaf(dq, dq, ss);
      stv.y = r4.y + (q4.y - r4.y); rsv.y = r4.y - q4.y; dq = q4.y - r4.y; ss = fmaf(dq, dq, ss);
      stv.z = r4.z + (q4.z - r4.z); rsv.z = r4.z - q4.z; dq = q4.z - r4.z; ss = fmaf(dq, dq, ss);
      stv.w = r4.w + (q4.w - r4.w); rsv.w = r4.w - q4.w; dq = q4.w - r4.w; ss = fmaf(dq, dq, ss);
      *(float4*)(out + ZQ_OFF  + zrow + u * 4) = stv;
      *(float4*)(out + RES_OFF + zrow + u * 4) = rsv;
    }
  }
  double dss = (double)ss;
  for (int o = 32; o; o >>= 1) dss += __shfl_down(dss, o, 64);
  if ((tid & 63) == 0) wred[tid >> 6] = dss;
  __syncthreads();
  if (tid == 0) bss[wg] = wred[0] + wred[1] + wred[2] + wred[3];
}

// ---------------- K3: scalars (loss, perplexity) ----------------------------
__global__ void vq10_final(const int* __restrict__ counts,
                           const double* __restrict__ bss,
                           float* __restrict__ out) {
  __shared__ double red[256];
  const int t = threadIdx.x;
  double s = 0.0;
  for (int i = t; i < 512; i += 256) s += bss[i];
  red[t] = s; __syncthreads();
  for (int s2 = 128; s2 > 0; s2 >>= 1) { if (t < s2) red[t] += red[t + s2]; __syncthreads(); }
  const double ssq = red[0];
  __syncthreads();
  double h = 0.0;
  for (int c = t; c < 1024; c += 256) {
    double p = (double)counts[c] / 131072.0;
    h += p * log(p + 1e-10);
  }
  red[t] = h; __syncthreads();
  for (int s2 = 128; s2 > 0; s2 >>= 1) { if (t < s2) red[t] += red[t + s2]; __syncthreads(); }
  if (t == 0) {
    out[LOSS_OFF] = (float)(0.25 * ssq / 33554432.0);
    out[PERP_OFF] = (float)exp(-red[0]);
  }
}

extern "C" void kernel_launch(void* const* d_in, const int* in_sizes, int n_in,
                              void* d_out, int out_size, void* d_ws, size_t ws_size,
                              hipStream_t stream) {
  // Bind inputs by SIZE: z has 33,554,432 elems, codebook 262,144.
  const float* z;
  const float* cb;
  if (in_sizes[0] == NR * DD) { z = (const float*)d_in[0]; cb = (const float*)d_in[1]; }
  else                        { cb = (const float*)d_in[0]; z = (const float*)d_in[1]; }

  float* out = (float*)d_out;
  char* ws = (char*)d_ws;
  int*    counts = (int*)(ws + WS_CNT);
  float*  c2n    = (float*)(ws + WS_C2N);
  float*  z2g    = (float*)(ws + WS_Z2);
  double* bss    = (double*)(ws + WS_BSS);

  hipMemsetAsync(counts, 0, 4096, stream);
  vq10_c2<<<4, 256, 0, stream>>>(cb, c2n);
  vq10_z2<<<NR / 16, 256, 0, stream>>>(z, z2g);
  vq10_main<<<NR / 256, 256, 0, stream>>>(z, cb, c2n, z2g, out, counts, bss);
  vq10_final<<<1, 256, 0, stream>>>(counts, bss, out);
}